// Round 1
// baseline (667.156 us; speedup 1.0000x reference)
//
#include <hip/hip_runtime.h>

typedef unsigned short u16;
typedef __bf16 bf16x8 __attribute__((ext_vector_type(8)));
typedef float f32x4 __attribute__((ext_vector_type(4)));

#define S_LEN 2048
#define NHEAD 16
#define QHEAD 192
#define EPS 1e-6f
#define ATTN_SCALE 0.07216878364870323f  /* 192^-0.5 */

__device__ __forceinline__ u16 f2bf(float f) {
    unsigned u = __builtin_bit_cast(unsigned, f);
    u = (u + 0x7FFFu + ((u >> 16) & 1u)) >> 16;
    return (u16)u;
}
__device__ __forceinline__ float bf2f(u16 h) {
    unsigned u = ((unsigned)h) << 16;
    return __builtin_bit_cast(float, u);
}

__device__ __forceinline__ void gl_lds16(const u16* g, u16* l) {
    __builtin_amdgcn_global_load_lds(
        (const __attribute__((address_space(1))) unsigned int*)g,
        (__attribute__((address_space(3))) unsigned int*)l,
        16, 0, 0);
}

// ---------------------------------------------------------------------------
// Batched bf16 GEMM:  C[M][N] = alpha * A[M][K] @ Bt[N][K]^T
// 128x128 block tile, BK=32, 4 waves (2x2), each wave 64x64 via 4x4 mfma tiles.
// causal: 0=none, 1=skip tiles with tn>tm (QK^T), 2=k-loop limit (PV with
// lower-triangular P).
// ---------------------------------------------------------------------------
template <int CF32>
__global__ __launch_bounds__(256, 2)
void gemm_bt(const u16* __restrict__ A, const u16* __restrict__ B,
             void* __restrict__ Cv, int K, int lda, int ldb, int ldc,
             long sA, long sB, long sC, float alpha, int causal)
{
    const int tid = threadIdx.x;
    const int wave = tid >> 6, lane = tid & 63;
    const int q = lane >> 4, r = lane & 15;
    const int tm = blockIdx.y, tn = blockIdx.x;
    if (causal == 1 && tn > tm) return;
    int kEnd = K;
    if (causal == 2) { int ke = (tm + 1) * 128; kEnd = ke < K ? ke : K; }
    const long batch = blockIdx.z;
    const u16* Ab = A + batch * sA;
    const u16* Bb = B + batch * sB;

    __shared__ __align__(16) u16 Al[128 * 32];
    __shared__ __align__(16) u16 Bl[128 * 32];

    const int lr = lane >> 2;          // 0..15: row within 16-row chunk
    const int lc = (lane & 3) * 8;     // k offset in elements
    const u16* ag0 = Ab + (long)(tm * 128 + wave * 32 + lr) * lda + lc;
    const u16* ag1 = ag0 + 16 * (long)lda;
    const u16* bg0 = Bb + (long)(tn * 128 + wave * 32 + lr) * ldb + lc;
    const u16* bg1 = bg0 + 16 * (long)ldb;
    u16* al0 = &Al[wave * 1024];
    u16* al1 = &Al[wave * 1024 + 512];
    u16* bl0 = &Bl[wave * 1024];
    u16* bl1 = &Bl[wave * 1024 + 512];

    f32x4 acc[4][4] = {};
    const int wm = (wave >> 1) * 64, wn = (wave & 1) * 64;
    const int aoff0 = (wm + r) * 32 + q * 8;
    const int boff0 = (wn + r) * 32 + q * 8;

    for (int k0 = 0; k0 < kEnd; k0 += 32) {
        gl_lds16(ag0 + k0, al0);
        gl_lds16(ag1 + k0, al1);
        gl_lds16(bg0 + k0, bl0);
        gl_lds16(bg1 + k0, bl1);
        __syncthreads();
        bf16x8 af[4], bv[4];
        #pragma unroll
        for (int mt = 0; mt < 4; ++mt) af[mt] = *(const bf16x8*)&Al[aoff0 + mt * 512];
        #pragma unroll
        for (int nt = 0; nt < 4; ++nt) bv[nt] = *(const bf16x8*)&Bl[boff0 + nt * 512];
        #pragma unroll
        for (int mt = 0; mt < 4; ++mt)
            #pragma unroll
            for (int nt = 0; nt < 4; ++nt)
                acc[mt][nt] = __builtin_amdgcn_mfma_f32_16x16x32_bf16(
                    af[mt], bv[nt], acc[mt][nt], 0, 0, 0);
        __syncthreads();
    }

    const int row0 = tm * 128 + wm + q * 4;
    const int col0 = tn * 128 + wn + r;
    if (CF32) {
        float* C = (float*)Cv + batch * sC;
        #pragma unroll
        for (int mt = 0; mt < 4; ++mt)
            #pragma unroll
            for (int i = 0; i < 4; ++i) {
                long rb = (long)(row0 + mt * 16 + i) * ldc + col0;
                #pragma unroll
                for (int nt = 0; nt < 4; ++nt)
                    C[rb + nt * 16] = acc[mt][nt][i] * alpha;
            }
    } else {
        u16* C = (u16*)Cv + batch * sC;
        #pragma unroll
        for (int mt = 0; mt < 4; ++mt)
            #pragma unroll
            for (int i = 0; i < 4; ++i) {
                long rb = (long)(row0 + mt * 16 + i) * ldc + col0;
                #pragma unroll
                for (int nt = 0; nt < 4; ++nt)
                    C[rb + nt * 16] = f2bf(acc[mt][nt][i] * alpha);
            }
    }
}

// ---------------------------------------------------------------------------
// fp32 -> bf16 (vectorized)
// ---------------------------------------------------------------------------
__global__ __launch_bounds__(256)
void cvt_f32_bf16(const float4* __restrict__ in, ushort4* __restrict__ out, int n4)
{
    int i = blockIdx.x * 256 + threadIdx.x;
    if (i < n4) {
        float4 v = in[i];
        ushort4 o;
        o.x = f2bf(v.x); o.y = f2bf(v.y); o.z = f2bf(v.z); o.w = f2bf(v.w);
        out[i] = o;
    }
}

// ---------------------------------------------------------------------------
// Weight transpose + convert: in fp32 [K][N] -> out bf16 [Npad][K] (rows >= N
// zero-filled). grid (K/32, Npad/32), block (32,8)
// ---------------------------------------------------------------------------
__global__ __launch_bounds__(256)
void wtrans_k(const float* __restrict__ in, u16* __restrict__ out, int K, int N)
{
    __shared__ float tile[32][33];
    int k0 = blockIdx.x * 32, n0 = blockIdx.y * 32;
    int tx = threadIdx.x, ty = threadIdx.y;
    #pragma unroll
    for (int j = 0; j < 32; j += 8) {
        int n = n0 + tx;
        tile[ty + j][tx] = (n < N) ? in[(long)(k0 + ty + j) * N + n] : 0.0f;
    }
    __syncthreads();
    #pragma unroll
    for (int j = 0; j < 32; j += 8)
        out[(long)(n0 + ty + j) * K + k0 + tx] = f2bf(tile[tx][ty + j]);
}

// ---------------------------------------------------------------------------
// Row-wise RMS norm (in-place), bf16 data, fp32 weight. grid = rows.
// ---------------------------------------------------------------------------
__global__ __launch_bounds__(256)
void rmsnorm_k(u16* __restrict__ X, const float* __restrict__ w, int D)
{
    u16* row = X + (long)blockIdx.x * D;
    const int tid = threadIdx.x;
    __shared__ float red[4];
    float sum = 0.f;
    for (int d = tid; d < D; d += 256) { float v = bf2f(row[d]); sum += v * v; }
    #pragma unroll
    for (int o = 32; o; o >>= 1) sum += __shfl_xor(sum, o, 64);
    if ((tid & 63) == 0) red[tid >> 6] = sum;
    __syncthreads();
    sum = red[0] + red[1] + red[2] + red[3];
    float scale = rsqrtf(sum / (float)D + EPS);
    for (int d = tid; d < D; d += 256)
        row[d] = f2bf(bf2f(row[d]) * scale * w[d]);
}

// ---------------------------------------------------------------------------
// ckv (bf16 [S][640], valid 576) -> kv_cache fp32 [S][576] (c_norm | roped
// k_pe), c_norm bf16 [S][512], k_pe broadcast into key[h][s][128:192].
// ---------------------------------------------------------------------------
__global__ __launch_bounds__(256)
void kvcache_k(const u16* __restrict__ ckv, const float* __restrict__ ln,
               const int* __restrict__ pos_ids, const float* __restrict__ cosb,
               const float* __restrict__ sinb, float* __restrict__ kvout,
               u16* __restrict__ cnb, u16* __restrict__ key)
{
    const int s = blockIdx.x, tid = threadIdx.x;
    const u16* row = ckv + (long)s * 640;
    __shared__ float red[4];
    float sum = 0.f;
    for (int d = tid; d < 512; d += 256) { float v = bf2f(row[d]); sum += v * v; }
    #pragma unroll
    for (int o = 32; o; o >>= 1) sum += __shfl_xor(sum, o, 64);
    if ((tid & 63) == 0) red[tid >> 6] = sum;
    __syncthreads();
    sum = red[0] + red[1] + red[2] + red[3];
    float scale = rsqrtf(sum / 512.f + EPS);
    for (int d = tid; d < 512; d += 256) {
        float v = bf2f(row[d]) * scale * ln[d];
        kvout[(long)s * 576 + d] = v;
        cnb[(long)s * 512 + d] = f2bf(v);
    }
    if (tid < 32) {
        int p = pos_ids[s];
        float x0 = bf2f(row[512 + 2 * tid]);
        float x1 = bf2f(row[512 + 2 * tid + 1]);
        float c1 = cosb[p * 64 + tid], s1 = sinb[p * 64 + tid];
        float c2 = cosb[p * 64 + 32 + tid], s2 = sinb[p * 64 + 32 + tid];
        float lo = x0 * c1 - x1 * s1;
        float hi = x1 * c2 + x0 * s2;
        kvout[(long)s * 576 + 512 + tid] = lo;
        kvout[(long)s * 576 + 544 + tid] = hi;
        u16 lob = f2bf(lo), hib = f2bf(hi);
        #pragma unroll
        for (int h = 0; h < NHEAD; ++h) {
            u16* kr = key + ((long)(h * S_LEN + s)) * QHEAD;
            kr[128 + tid] = lob;
            kr[160 + tid] = hib;
        }
    }
}

// ---------------------------------------------------------------------------
// q (bf16 [S][3072]) -> query bf16 [H][S][192] with rope on last 64 dims.
// ---------------------------------------------------------------------------
__global__ __launch_bounds__(256)
void qrope_k(const u16* __restrict__ qb, const int* __restrict__ pos_ids,
             const float* __restrict__ cosb, const float* __restrict__ sinb,
             u16* __restrict__ query)
{
    const int s = blockIdx.x, tid = threadIdx.x;
    const u16* row = qb + (long)s * 3072;
    for (int idx = tid; idx < 2048; idx += 256) {
        int h = idx >> 7, d = idx & 127;
        query[((long)(h * S_LEN + s)) * QHEAD + d] = row[h * QHEAD + d];
    }
    int p = pos_ids[s];
    for (int idx = tid; idx < 512; idx += 256) {
        int h = idx >> 5, i = idx & 31;
        float x0 = bf2f(row[h * QHEAD + 128 + 2 * i]);
        float x1 = bf2f(row[h * QHEAD + 128 + 2 * i + 1]);
        float c1 = cosb[p * 64 + i], s1 = sinb[p * 64 + i];
        float c2 = cosb[p * 64 + 32 + i], s2 = sinb[p * 64 + 32 + i];
        u16* qr = query + ((long)(h * S_LEN + s)) * QHEAD;
        qr[128 + i] = f2bf(x0 * c1 - x1 * s1);
        qr[160 + i] = f2bf(x1 * c2 + x0 * s2);
    }
}

// ---------------------------------------------------------------------------
// kv bf16 [S][4096] -> key[h][s][0:128] (k_nope)
// ---------------------------------------------------------------------------
__global__ __launch_bounds__(256)
void knope_k(const u16* __restrict__ kv, u16* __restrict__ key)
{
    int idx = blockIdx.x * 256 + threadIdx.x;
    int s = idx >> 11, rem = idx & 2047;
    int h = rem >> 7, d = rem & 127;
    key[((long)(h * S_LEN + s)) * QHEAD + d] = kv[((long)s << 12) + (h << 8) + d];
}

// ---------------------------------------------------------------------------
// kv bf16 [S][4096] value part -> vt bf16 [H*128][S] (transposed)
// grid (S/32, 128/32, H), block (32,8)
// ---------------------------------------------------------------------------
__global__ __launch_bounds__(256)
void vtrans_k(const u16* __restrict__ kv, u16* __restrict__ vt)
{
    __shared__ u16 tile[32][33];
    int s0 = blockIdx.x * 32, d0 = blockIdx.y * 32, h = blockIdx.z;
    int tx = threadIdx.x, ty = threadIdx.y;
    #pragma unroll
    for (int j = 0; j < 32; j += 8)
        tile[ty + j][tx] = kv[(long)(s0 + ty + j) * 4096 + h * 256 + 128 + d0 + tx];
    __syncthreads();
    #pragma unroll
    for (int j = 0; j < 32; j += 8)
        vt[(long)(h * 128 + d0 + ty + j) * S_LEN + s0 + tx] = tile[tx][ty + j];
}

// ---------------------------------------------------------------------------
// Causal softmax, in-place on bf16 scores [G][S][S]; row = (blockIdx.y head,
// blockIdx.x = s). Valid cols [0, s]; zeros elsewhere.
// ---------------------------------------------------------------------------
__global__ __launch_bounds__(256)
void softmax_causal(u16* __restrict__ Sb, long headStride)
{
    const int s = blockIdx.x, tid = threadIdx.x;
    u16* row = Sb + (long)blockIdx.y * headStride + (long)s * S_LEN;
    __shared__ float red[4];
    float mx = -3.0e38f;
    for (int t = tid; t <= s; t += 256) mx = fmaxf(mx, bf2f(row[t]));
    #pragma unroll
    for (int o = 32; o; o >>= 1) mx = fmaxf(mx, __shfl_xor(mx, o, 64));
    if ((tid & 63) == 0) red[tid >> 6] = mx;
    __syncthreads();
    mx = fmaxf(fmaxf(red[0], red[1]), fmaxf(red[2], red[3]));
    __syncthreads();
    float sum = 0.f;
    for (int t = tid; t <= s; t += 256) sum += __expf(bf2f(row[t]) - mx);
    #pragma unroll
    for (int o = 32; o; o >>= 1) sum += __shfl_xor(sum, o, 64);
    if ((tid & 63) == 0) red[tid >> 6] = sum;
    __syncthreads();
    sum = red[0] + red[1] + red[2] + red[3];
    float inv = 1.0f / sum;
    for (int t = tid; t < S_LEN; t += 256)
        row[t] = (t <= s) ? f2bf(__expf(bf2f(row[t]) - mx) * inv) : (u16)0;
}

// ---------------------------------------------------------------------------
extern "C" void kernel_launch(void* const* d_in, const int* in_sizes, int n_in,
                              void* d_out, int out_size, void* d_ws, size_t ws_size,
                              hipStream_t stream)
{
    const float* x      = (const float*)d_in[0];
    const int*   posid  = (const int*)d_in[2];
    const float* cosb   = (const float*)d_in[3];
    const float* sinb   = (const float*)d_in[4];
    const float* q_a_w  = (const float*)d_in[5];
    const float* q_a_ln = (const float*)d_in[6];
    const float* q_b_w  = (const float*)d_in[7];
    const float* kv_a_w = (const float*)d_in[8];
    const float* kv_a_ln= (const float*)d_in[9];
    const float* kv_b_w = (const float*)d_in[10];
    const float* o_w    = (const float*)d_in[11];

    float* out    = (float*)d_out;
    float* kv_out = out + (size_t)2048 * 2048;

    // ---- workspace arena ----
    char* ws = (char*)d_ws;
    size_t off = 0;
    auto alloc = [&](size_t bytes) { char* p = ws + off; off += (bytes + 255) & ~(size_t)255; return p; };
    u16* xb    = (u16*)alloc(2048ULL * 2048 * 2);
    u16* qawt  = (u16*)alloc(1536ULL * 2048 * 2);
    u16* qbwt  = (u16*)alloc(3072ULL * 1536 * 2);
    u16* kvawt = (u16*)alloc(640ULL * 2048 * 2);
    u16* kvbwt = (u16*)alloc(4096ULL * 512 * 2);
    u16* owt   = (u16*)alloc(2048ULL * 2048 * 2);
    u16* qa    = (u16*)alloc(2048ULL * 1536 * 2);
    u16* qbuf  = (u16*)alloc(2048ULL * 3072 * 2);
    u16* query = (u16*)alloc(16ULL * 2048 * 192 * 2);
    u16* ckv   = (u16*)alloc(2048ULL * 640 * 2);
    u16* cnb   = (u16*)alloc(2048ULL * 512 * 2);
    u16* key   = (u16*)alloc(16ULL * 2048 * 192 * 2);
    u16* kvbuf = (u16*)alloc(2048ULL * 4096 * 2);
    u16* vt    = (u16*)alloc(16ULL * 128 * 2048 * 2);
    u16* ao    = (u16*)alloc(2048ULL * 2048 * 2);
    u16* Sbuf  = (u16*)alloc(4ULL * 2048 * 2048 * 2);
    (void)ws_size; (void)in_sizes; (void)n_in; (void)out_size;

    dim3 blk(256);
    dim3 tblk(32, 8);

    // 0) conversions
    cvt_f32_bf16<<<dim3(4096), blk, 0, stream>>>((const float4*)x, (ushort4*)xb, 2048 * 2048 / 4);
    wtrans_k<<<dim3(64, 48),  tblk, 0, stream>>>(q_a_w,  qawt,  2048, 1536);
    wtrans_k<<<dim3(48, 96),  tblk, 0, stream>>>(q_b_w,  qbwt,  1536, 3072);
    wtrans_k<<<dim3(64, 20),  tblk, 0, stream>>>(kv_a_w, kvawt, 2048, 576);
    wtrans_k<<<dim3(16, 128), tblk, 0, stream>>>(kv_b_w, kvbwt, 512,  4096);
    wtrans_k<<<dim3(64, 64),  tblk, 0, stream>>>(o_w,    owt,   2048, 2048);

    // 1) q_a = x @ q_a_w ; RMS norm (in-place)
    gemm_bt<0><<<dim3(12, 16, 1), blk, 0, stream>>>(xb, qawt, qa, 2048, 2048, 2048, 1536, 0, 0, 0, 1.0f, 0);
    rmsnorm_k<<<dim3(2048), blk, 0, stream>>>(qa, q_a_ln, 1536);

    // 2) q = q_a_norm @ q_b_w ; rope + relayout
    gemm_bt<0><<<dim3(24, 16, 1), blk, 0, stream>>>(qa, qbwt, qbuf, 1536, 1536, 1536, 3072, 0, 0, 0, 1.0f, 0);
    qrope_k<<<dim3(2048), blk, 0, stream>>>(qbuf, posid, cosb, sinb, query);

    // 3) ckv = x @ kv_a_w ; kv_cache + c_norm + k_pe rope
    gemm_bt<0><<<dim3(5, 16, 1), blk, 0, stream>>>(xb, kvawt, ckv, 2048, 2048, 2048, 640, 0, 0, 0, 1.0f, 0);
    kvcache_k<<<dim3(2048), blk, 0, stream>>>(ckv, kv_a_ln, posid, cosb, sinb, kv_out, cnb, key);

    // 4) kv = c_norm @ kv_b_w ; relayout k_nope + transpose value
    gemm_bt<0><<<dim3(32, 16, 1), blk, 0, stream>>>(cnb, kvbwt, kvbuf, 512, 512, 512, 4096, 0, 0, 0, 1.0f, 0);
    knope_k<<<dim3(16384), blk, 0, stream>>>(kvbuf, key);
    vtrans_k<<<dim3(64, 4, 16), tblk, 0, stream>>>(kvbuf, vt);

    // 5) attention in 4 head-groups of 4
    for (int g = 0; g < 4; ++g) {
        int h0 = g * 4;
        gemm_bt<0><<<dim3(16, 16, 4), blk, 0, stream>>>(
            query + (size_t)h0 * S_LEN * QHEAD, key + (size_t)h0 * S_LEN * QHEAD, Sbuf,
            QHEAD, QHEAD, QHEAD, S_LEN,
            (long)S_LEN * QHEAD, (long)S_LEN * QHEAD, (long)S_LEN * S_LEN,
            ATTN_SCALE, 1);
        softmax_causal<<<dim3(2048, 4), blk, 0, stream>>>(Sbuf, (long)S_LEN * S_LEN);
        gemm_bt<0><<<dim3(1, 16, 4), blk, 0, stream>>>(
            Sbuf, vt + (size_t)h0 * 128 * S_LEN, ao + h0 * 128,
            S_LEN, S_LEN, S_LEN, 2048,
            (long)S_LEN * S_LEN, (long)128 * S_LEN, 128L,
            1.0f, 2);
    }

    // 6) out = ao @ o_w   (fp32 output)
    gemm_bt<1><<<dim3(16, 16, 1), blk, 0, stream>>>(ao, owt, out, 2048, 2048, 2048, 2048, 0, 0, 0, 1.0f, 0);
}

// Round 2
// 516.259 us; speedup vs baseline: 1.2923x; 1.2923x over previous
//
#include <hip/hip_runtime.h>

typedef unsigned short u16;
typedef __bf16 bf16x8 __attribute__((ext_vector_type(8)));
typedef float f32x4 __attribute__((ext_vector_type(4)));

#define S_LEN 2048
#define NHEAD 16
#define QHEAD 192
#define EPS 1e-6f
#define ATTN_SCALE 0.07216878364870323f  /* 192^-0.5 */

__device__ __forceinline__ u16 f2bf(float f) {
    unsigned u = __builtin_bit_cast(unsigned, f);
    u = (u + 0x7FFFu + ((u >> 16) & 1u)) >> 16;
    return (u16)u;
}
__device__ __forceinline__ float bf2f(u16 h) {
    unsigned u = ((unsigned)h) << 16;
    return __builtin_bit_cast(float, u);
}

__device__ __forceinline__ void gl_lds16(const u16* g, u16* l) {
    __builtin_amdgcn_global_load_lds(
        (const __attribute__((address_space(1))) unsigned int*)g,
        (__attribute__((address_space(3))) unsigned int*)l,
        16, 0, 0);
}

// ---------------------------------------------------------------------------
// bf16 GEMM:  C[M][N] = A[M][K] @ Bt[N][K]^T
// 128x128 tile, BK=32, 4 waves (2x2), each wave 64x64 via 4x4 mfma tiles.
// LDS layout: 16-row chunks of 512 u16; within a chunk lane l holds
// (row = l&15, k = (l>>4)*8 .. +7) -> fragment reads are chunk + lane*16B
// (2-way bank alias only, free).
// ---------------------------------------------------------------------------
template <int CF32>
__global__ __launch_bounds__(256, 2)
void gemm_bt(const u16* __restrict__ A, const u16* __restrict__ B,
             void* __restrict__ Cv, int K, int lda, int ldb, int ldc)
{
    const int tid = threadIdx.x;
    const int wave = tid >> 6, lane = tid & 63;
    const int q = lane >> 4, r = lane & 15;
    const int tm = blockIdx.y, tn = blockIdx.x;

    __shared__ __align__(16) u16 Al[128 * 32];
    __shared__ __align__(16) u16 Bl[128 * 32];

    const int lr = lane & 15;          // row within 16-row chunk
    const int lc = (lane >> 4) * 8;    // k offset in elements
    const u16* ag0 = A + (long)(tm * 128 + wave * 32 + lr) * lda + lc;
    const u16* ag1 = ag0 + 16 * (long)lda;
    const u16* bg0 = B + (long)(tn * 128 + wave * 32 + lr) * ldb + lc;
    const u16* bg1 = bg0 + 16 * (long)ldb;
    u16* al0 = &Al[wave * 1024];
    u16* al1 = &Al[wave * 1024 + 512];
    u16* bl0 = &Bl[wave * 1024];
    u16* bl1 = &Bl[wave * 1024 + 512];

    f32x4 acc[4][4] = {};
    const int cm = (wave >> 1) * 4;    // chunk index base for m
    const int cn = (wave & 1) * 4;     // chunk index base for n

    for (int k0 = 0; k0 < K; k0 += 32) {
        gl_lds16(ag0 + k0, al0);
        gl_lds16(ag1 + k0, al1);
        gl_lds16(bg0 + k0, bl0);
        gl_lds16(bg1 + k0, bl1);
        __syncthreads();
        bf16x8 af[4], bv[4];
        #pragma unroll
        for (int mt = 0; mt < 4; ++mt) af[mt] = *(const bf16x8*)&Al[(cm + mt) * 512 + lane * 8];
        #pragma unroll
        for (int nt = 0; nt < 4; ++nt) bv[nt] = *(const bf16x8*)&Bl[(cn + nt) * 512 + lane * 8];
        #pragma unroll
        for (int mt = 0; mt < 4; ++mt)
            #pragma unroll
            for (int nt = 0; nt < 4; ++nt)
                acc[mt][nt] = __builtin_amdgcn_mfma_f32_16x16x32_bf16(
                    af[mt], bv[nt], acc[mt][nt], 0, 0, 0);
        __syncthreads();
    }

    const int wm = (wave >> 1) * 64, wn = (wave & 1) * 64;
    const int row0 = tm * 128 + wm + q * 4;
    const int col0 = tn * 128 + wn + r;
    if (CF32) {
        float* C = (float*)Cv;
        #pragma unroll
        for (int mt = 0; mt < 4; ++mt)
            #pragma unroll
            for (int i = 0; i < 4; ++i) {
                long rb = (long)(row0 + mt * 16 + i) * ldc + col0;
                #pragma unroll
                for (int nt = 0; nt < 4; ++nt)
                    C[rb + nt * 16] = acc[mt][nt][i];
            }
    } else {
        u16* C = (u16*)Cv;
        #pragma unroll
        for (int mt = 0; mt < 4; ++mt)
            #pragma unroll
            for (int i = 0; i < 4; ++i) {
                long rb = (long)(row0 + mt * 16 + i) * ldc + col0;
                #pragma unroll
                for (int nt = 0; nt < 4; ++nt)
                    C[rb + nt * 16] = f2bf(acc[mt][nt][i]);
            }
    }
}

// ---------------------------------------------------------------------------
// Fused flash attention. grid (16 q-tiles, 16 heads), block 256 (4 waves).
// Each wave owns a 32-row strip of the 128-row q-tile; loops kv-tiles 0..tq.
// K-tile staged into S1 (48KB) from kvbuf (k_nope) + kpe; after QK^T the same
// S1 region is re-staged with the V-tile (from vt, d-major). P goes C->A
// layout through wave-private Pl.
// ---------------------------------------------------------------------------
__global__ __launch_bounds__(256, 1)
void flash_attn(const u16* __restrict__ query, const u16* __restrict__ kvb,
                const u16* __restrict__ kpe, const u16* __restrict__ vt,
                u16* __restrict__ ao)
{
    const int tid = threadIdx.x;
    const int w = tid >> 6, lane = tid & 63;
    const int qd = lane >> 4, r = lane & 15;
    const int tq = 15 - blockIdx.x;    // heavy tiles launch first
    const int h  = blockIdx.y;

    __shared__ __align__(16) u16 S1[24576];   // 48KB staging (K then V)
    __shared__ __align__(16) u16 Pl[8192];    // 16KB, 4KB per wave

    // Q fragments (A-layout), resident in registers: rows w*32+mt*16+(lane&15)
    bf16x8 aq[2][6];
    {
        const u16* qb = query + ((long)(h * S_LEN + tq * 128 + w * 32 + r)) * QHEAD + qd * 8;
        #pragma unroll
        for (int mt = 0; mt < 2; ++mt)
            #pragma unroll
            for (int kc = 0; kc < 6; ++kc)
                aq[mt][kc] = *(const bf16x8*)(qb + mt * 16 * QHEAD + kc * 32);
    }

    f32x4 Oacc[2][8] = {};
    float mrow[2][4], lrow[2][4];
    #pragma unroll
    for (int mt = 0; mt < 2; ++mt)
        #pragma unroll
        for (int i = 0; i < 4; ++i) { mrow[mt][i] = -3.0e38f; lrow[mt][i] = 0.f; }

    u16* PlW = Pl + w * 2048;

    for (int tk = 0; tk <= tq; ++tk) {
        // ---- stage K-tile: 48 chunks (nt 0..7 x kc 0..5), wave w does 12 ----
        #pragma unroll
        for (int c = 0; c < 12; ++c) {
            int g = w * 12 + c;
            int nt = g / 6, kc = g % 6;
            const u16* src;
            if (kc < 4)
                src = kvb + ((long)(tk * 128 + nt * 16 + r)) * 4096 + h * 256 + kc * 32 + qd * 8;
            else
                src = kpe + ((long)(tk * 128 + nt * 16 + r)) * 64 + (kc - 4) * 32 + qd * 8;
            gl_lds16(src, &S1[g * 512]);
        }
        __syncthreads();

        // ---- S = Q @ K^T ----
        f32x4 Sacc[2][8] = {};
        #pragma unroll
        for (int kc = 0; kc < 6; ++kc) {
            bf16x8 bk[8];
            #pragma unroll
            for (int nt = 0; nt < 8; ++nt)
                bk[nt] = *(const bf16x8*)&S1[(nt * 6 + kc) * 512 + lane * 8];
            #pragma unroll
            for (int mt = 0; mt < 2; ++mt)
                #pragma unroll
                for (int nt = 0; nt < 8; ++nt)
                    Sacc[mt][nt] = __builtin_amdgcn_mfma_f32_16x16x32_bf16(
                        aq[mt][kc], bk[nt], Sacc[mt][nt], 0, 0, 0);
        }

        // ---- online softmax; lane holds rows mt*16+qd*4+i, col nt*16+r ----
        float alf[2][4];
        #pragma unroll
        for (int mt = 0; mt < 2; ++mt)
            #pragma unroll
            for (int i = 0; i < 4; ++i) {
                float mx = -3.0e38f;
                int rowl = w * 32 + mt * 16 + qd * 4 + i;
                #pragma unroll
                for (int nt = 0; nt < 8; ++nt) {
                    float v = Sacc[mt][nt][i] * ATTN_SCALE;
                    if (tk == tq && nt * 16 + r > rowl) v = -3.0e38f;
                    Sacc[mt][nt][i] = v;
                    mx = fmaxf(mx, v);
                }
                #pragma unroll
                for (int o = 1; o < 16; o <<= 1) mx = fmaxf(mx, __shfl_xor(mx, o, 64));
                float mold = mrow[mt][i];
                float mnew = fmaxf(mold, mx);
                mrow[mt][i] = mnew;
                float al = __expf(mold - mnew);
                alf[mt][i] = al;
                float sum = 0.f;
                #pragma unroll
                for (int nt = 0; nt < 8; ++nt) {
                    float p = __expf(Sacc[mt][nt][i] - mnew);
                    Sacc[mt][nt][i] = p;
                    sum += p;
                }
                #pragma unroll
                for (int o = 1; o < 16; o <<= 1) sum += __shfl_xor(sum, o, 64);
                lrow[mt][i] = lrow[mt][i] * al + sum;
                #pragma unroll
                for (int nt = 0; nt < 8; ++nt)
                    Oacc[mt][nt][i] *= al;
            }
        __syncthreads();   // everyone done reading K

        // ---- stage V-tile: 32 chunks (ntv 0..7 x kcv 0..3), wave w does 8 ----
        #pragma unroll
        for (int c = 0; c < 8; ++c) {
            int g = w * 8 + c;
            int ntv = g >> 2, kcv = g & 3;
            const u16* src = vt + ((long)(h * 128 + ntv * 16 + r)) * S_LEN
                             + tk * 128 + kcv * 32 + qd * 8;
            gl_lds16(src, &S1[g * 512]);
        }
        __syncthreads();

        // ---- O += P @ V  (P: C-layout -> A-layout via wave-private LDS) ----
        #pragma unroll
        for (int mt = 0; mt < 2; ++mt) {
            #pragma unroll
            for (int nt = 0; nt < 8; ++nt) {
                int base = (nt >> 1) * 512
                         + (((nt & 1) * 2 + (r >> 3)) * 16 + qd * 4) * 8 + (r & 7);
                #pragma unroll
                for (int i = 0; i < 4; ++i)
                    PlW[base + i * 8] = f2bf(Sacc[mt][nt][i]);
            }
            #pragma unroll
            for (int kcp = 0; kcp < 4; ++kcp) {
                bf16x8 pa = *(const bf16x8*)&PlW[kcp * 512 + lane * 8];
                #pragma unroll
                for (int nt = 0; nt < 8; ++nt) {
                    bf16x8 bvv = *(const bf16x8*)&S1[(nt * 4 + kcp) * 512 + lane * 8];
                    Oacc[mt][nt] = __builtin_amdgcn_mfma_f32_16x16x32_bf16(
                        pa, bvv, Oacc[mt][nt], 0, 0, 0);
                }
            }
        }
        __syncthreads();   // everyone done reading V before next K staging
    }

    // ---- epilogue: O /= l, write ao[s][h*128+d] ----
    #pragma unroll
    for (int mt = 0; mt < 2; ++mt)
        #pragma unroll
        for (int i = 0; i < 4; ++i) {
            float inv = 1.0f / lrow[mt][i];
            int row = tq * 128 + w * 32 + mt * 16 + qd * 4 + i;
            u16* dst = ao + (long)row * 2048 + h * 128 + r;
            #pragma unroll
            for (int nt = 0; nt < 8; ++nt)
                dst[nt * 16] = f2bf(Oacc[mt][nt][i] * inv);
        }
}

// ---------------------------------------------------------------------------
__global__ __launch_bounds__(256)
void cvt_f32_bf16(const float4* __restrict__ in, ushort4* __restrict__ out, int n4)
{
    int i = blockIdx.x * 256 + threadIdx.x;
    if (i < n4) {
        float4 v = in[i];
        ushort4 o;
        o.x = f2bf(v.x); o.y = f2bf(v.y); o.z = f2bf(v.z); o.w = f2bf(v.w);
        out[i] = o;
    }
}

// in fp32 [K][N] -> out bf16 [Npad][K], rows >= N zero-filled.
__global__ __launch_bounds__(256)
void wtrans_k(const float* __restrict__ in, u16* __restrict__ out, int K, int N)
{
    __shared__ float tile[32][33];
    int k0 = blockIdx.x * 32, n0 = blockIdx.y * 32;
    int tx = threadIdx.x, ty = threadIdx.y;
    #pragma unroll
    for (int j = 0; j < 32; j += 8) {
        int n = n0 + tx;
        tile[ty + j][tx] = (n < N) ? in[(long)(k0 + ty + j) * N + n] : 0.0f;
    }
    __syncthreads();
    #pragma unroll
    for (int j = 0; j < 32; j += 8)
        out[(long)(n0 + ty + j) * K + k0 + tx] = f2bf(tile[tx][ty + j]);
}

// RMS norm in-place on first D cols of rows with stride ld.
__global__ __launch_bounds__(256)
void rmsnorm_k(u16* __restrict__ X, const float* __restrict__ w, int D, int ld)
{
    u16* row = X + (long)blockIdx.x * ld;
    const int tid = threadIdx.x;
    __shared__ float red[4];
    float sum = 0.f;
    for (int d = tid; d < D; d += 256) { float v = bf2f(row[d]); sum += v * v; }
    #pragma unroll
    for (int o = 32; o; o >>= 1) sum += __shfl_xor(sum, o, 64);
    if ((tid & 63) == 0) red[tid >> 6] = sum;
    __syncthreads();
    sum = red[0] + red[1] + red[2] + red[3];
    float scale = rsqrtf(sum / (float)D + EPS);
    for (int d = tid; d < D; d += 256)
        row[d] = f2bf(bf2f(row[d]) * scale * w[d]);
}

// qkv_a bf16 [S][2176] cols 1536.. = [c(512)|k_pe(64)] -> kv_cache fp32
// [S][576], c_norm bf16 [S][512], roped k_pe bf16 [S][64].
__global__ __launch_bounds__(256)
void kvcache_k(const u16* __restrict__ qkv, const float* __restrict__ ln,
               const int* __restrict__ pos_ids, const float* __restrict__ cosb,
               const float* __restrict__ sinb, float* __restrict__ kvout,
               u16* __restrict__ cnb, u16* __restrict__ kpe)
{
    const int s = blockIdx.x, tid = threadIdx.x;
    const u16* row = qkv + (long)s * 2176 + 1536;
    __shared__ float red[4];
    float sum = 0.f;
    for (int d = tid; d < 512; d += 256) { float v = bf2f(row[d]); sum += v * v; }
    #pragma unroll
    for (int o = 32; o; o >>= 1) sum += __shfl_xor(sum, o, 64);
    if ((tid & 63) == 0) red[tid >> 6] = sum;
    __syncthreads();
    sum = red[0] + red[1] + red[2] + red[3];
    float scale = rsqrtf(sum / 512.f + EPS);
    for (int d = tid; d < 512; d += 256) {
        float v = bf2f(row[d]) * scale * ln[d];
        kvout[(long)s * 576 + d] = v;
        cnb[(long)s * 512 + d] = f2bf(v);
    }
    if (tid < 32) {
        int p = pos_ids[s];
        float x0 = bf2f(row[512 + 2 * tid]);
        float x1 = bf2f(row[512 + 2 * tid + 1]);
        float c1 = cosb[p * 64 + tid], s1 = sinb[p * 64 + tid];
        float c2 = cosb[p * 64 + 32 + tid], s2 = sinb[p * 64 + 32 + tid];
        float lo = x0 * c1 - x1 * s1;
        float hi = x1 * c2 + x0 * s2;
        kvout[(long)s * 576 + 512 + tid] = lo;
        kvout[(long)s * 576 + 544 + tid] = hi;
        kpe[(long)s * 64 + tid] = f2bf(lo);
        kpe[(long)s * 64 + 32 + tid] = f2bf(hi);
    }
}

// q bf16 [S][3072] -> query bf16 [H][S][192], rope on last 64 dims.
__global__ __launch_bounds__(256)
void qrope_k(const u16* __restrict__ qb, const int* __restrict__ pos_ids,
             const float* __restrict__ cosb, const float* __restrict__ sinb,
             u16* __restrict__ query)
{
    const int s = blockIdx.x, tid = threadIdx.x;
    const u16* row = qb + (long)s * 3072;
    {   // nope part: 16 heads x 16 chunks of 8
        int h = tid >> 4, c = tid & 15;
        *(bf16x8*)&query[((long)(h * S_LEN + s)) * QHEAD + c * 8] =
            *(const bf16x8*)&row[h * QHEAD + c * 8];
    }
    int p = pos_ids[s];
    for (int idx = tid; idx < 512; idx += 256) {
        int h = idx >> 5, i = idx & 31;
        float x0 = bf2f(row[h * QHEAD + 128 + 2 * i]);
        float x1 = bf2f(row[h * QHEAD + 128 + 2 * i + 1]);
        float c1 = cosb[p * 64 + i], s1 = sinb[p * 64 + i];
        float c2 = cosb[p * 64 + 32 + i], s2 = sinb[p * 64 + 32 + i];
        u16* qr = query + ((long)(h * S_LEN + s)) * QHEAD;
        qr[128 + i] = f2bf(x0 * c1 - x1 * s1);
        qr[160 + i] = f2bf(x1 * c2 + x0 * s2);
    }
}

// kv bf16 [S][4096] value part -> vt bf16 [H*128][S] (transposed)
__global__ __launch_bounds__(256)
void vtrans_k(const u16* __restrict__ kv, u16* __restrict__ vt)
{
    __shared__ u16 tile[32][33];
    int s0 = blockIdx.x * 32, d0 = blockIdx.y * 32, h = blockIdx.z;
    int tx = threadIdx.x, ty = threadIdx.y;
    #pragma unroll
    for (int j = 0; j < 32; j += 8)
        tile[ty + j][tx] = kv[(long)(s0 + ty + j) * 4096 + h * 256 + 128 + d0 + tx];
    __syncthreads();
    #pragma unroll
    for (int j = 0; j < 32; j += 8)
        vt[(long)(h * 128 + d0 + ty + j) * S_LEN + s0 + tx] = tile[tx][ty + j];
}

// ---------------------------------------------------------------------------
extern "C" void kernel_launch(void* const* d_in, const int* in_sizes, int n_in,
                              void* d_out, int out_size, void* d_ws, size_t ws_size,
                              hipStream_t stream)
{
    const float* x      = (const float*)d_in[0];
    const int*   posid  = (const int*)d_in[2];
    const float* cosb   = (const float*)d_in[3];
    const float* sinb   = (const float*)d_in[4];
    const float* q_a_w  = (const float*)d_in[5];
    const float* q_a_ln = (const float*)d_in[6];
    const float* q_b_w  = (const float*)d_in[7];
    const float* kv_a_w = (const float*)d_in[8];
    const float* kv_a_ln= (const float*)d_in[9];
    const float* kv_b_w = (const float*)d_in[10];
    const float* o_w    = (const float*)d_in[11];

    float* out    = (float*)d_out;
    float* kv_out = out + (size_t)2048 * 2048;

    char* ws = (char*)d_ws;
    size_t off = 0;
    auto alloc = [&](size_t bytes) { char* p = ws + off; off += (bytes + 255) & ~(size_t)255; return p; };
    u16* xb    = (u16*)alloc(2048ULL * 2048 * 2);
    u16* W1    = (u16*)alloc(2176ULL * 2048 * 2);   // [q_a^T ; kv_a^T(pad 640)]
    u16* qbwt  = (u16*)alloc(3072ULL * 1536 * 2);
    u16* kvbwt = (u16*)alloc(4096ULL * 512 * 2);
    u16* owt   = (u16*)alloc(2048ULL * 2048 * 2);
    u16* qkv_a = (u16*)alloc(2048ULL * 2176 * 2);   // [q_a(1536) | ckv(640)]
    u16* qbuf  = (u16*)alloc(2048ULL * 3072 * 2);
    u16* query = (u16*)alloc(16ULL * 2048 * 192 * 2);
    u16* cnb   = (u16*)alloc(2048ULL * 512 * 2);
    u16* kpe   = (u16*)alloc(2048ULL * 64 * 2);
    u16* kvbuf = (u16*)alloc(2048ULL * 4096 * 2);
    u16* vt    = (u16*)alloc(16ULL * 128 * 2048 * 2);
    u16* ao    = (u16*)alloc(2048ULL * 2048 * 2);
    (void)ws_size; (void)in_sizes; (void)n_in; (void)out_size;

    dim3 blk(256);
    dim3 tblk(32, 8);

    // 0) conversions / weight transposes
    cvt_f32_bf16<<<dim3(4096), blk, 0, stream>>>((const float4*)x, (ushort4*)xb, 2048 * 2048 / 4);
    wtrans_k<<<dim3(64, 48),  tblk, 0, stream>>>(q_a_w,  W1,                    2048, 1536);
    wtrans_k<<<dim3(64, 20),  tblk, 0, stream>>>(kv_a_w, W1 + 1536ULL * 2048,   2048, 576);
    wtrans_k<<<dim3(48, 96),  tblk, 0, stream>>>(q_b_w,  qbwt,  1536, 3072);
    wtrans_k<<<dim3(16, 128), tblk, 0, stream>>>(kv_b_w, kvbwt, 512,  4096);
    wtrans_k<<<dim3(64, 64),  tblk, 0, stream>>>(o_w,    owt,   2048, 2048);

    // 1) [q_a | ckv] = x @ [q_a_w | kv_a_w]  (merged, N=2176)
    gemm_bt<0><<<dim3(17, 16), blk, 0, stream>>>(xb, W1, qkv_a, 2048, 2048, 2048, 2176);
    rmsnorm_k<<<dim3(2048), blk, 0, stream>>>(qkv_a, q_a_ln, 1536, 2176);
    kvcache_k<<<dim3(2048), blk, 0, stream>>>(qkv_a, kv_a_ln, posid, cosb, sinb, kv_out, cnb, kpe);

    // 2) q = q_a_norm @ q_b_w ; rope + relayout
    gemm_bt<0><<<dim3(24, 16), blk, 0, stream>>>(qkv_a, qbwt, qbuf, 1536, 2176, 1536, 3072);
    qrope_k<<<dim3(2048), blk, 0, stream>>>(qbuf, posid, cosb, sinb, query);

    // 3) kv = c_norm @ kv_b_w ; transpose value
    gemm_bt<0><<<dim3(32, 16), blk, 0, stream>>>(cnb, kvbwt, kvbuf, 512, 512, 512, 4096);
    vtrans_k<<<dim3(64, 4, 16), tblk, 0, stream>>>(kvbuf, vt);

    // 4) fused flash attention -> ao bf16 [S][H*128]
    flash_attn<<<dim3(16, 16), blk, 0, stream>>>(query, kvbuf, kpe, vt, ao);

    // 5) out = ao @ o_w (fp32)
    gemm_bt<1><<<dim3(16, 16), blk, 0, stream>>>(ao, owt, out, 2048, 2048, 2048, 2048);
}

// Round 3
// 497.435 us; speedup vs baseline: 1.3412x; 1.0378x over previous
//
#include <hip/hip_runtime.h>

typedef unsigned short u16;
typedef __bf16 bf16x8 __attribute__((ext_vector_type(8)));
typedef short s16x4 __attribute__((ext_vector_type(4)));
typedef float f32x4 __attribute__((ext_vector_type(4)));

#define S_LEN 2048
#define NHEAD 16
#define QHEAD 192
#define EPS 1e-6f
#define ATTN_SCALE 0.07216878364870323f   /* 192^-0.5 */
#define QSCALE_LOG2E 0.10412011228586118f /* ATTN_SCALE * log2(e) */

__device__ __forceinline__ u16 f2bf(float f) {
    unsigned u = __builtin_bit_cast(unsigned, f);
    u = (u + 0x7FFFu + ((u >> 16) & 1u)) >> 16;
    return (u16)u;
}
__device__ __forceinline__ float bf2f(u16 h) {
    unsigned u = ((unsigned)h) << 16;
    return __builtin_bit_cast(float, u);
}

__device__ __forceinline__ void gl_lds16(const u16* g, u16* l) {
    __builtin_amdgcn_global_load_lds(
        (const __attribute__((address_space(1))) unsigned int*)g,
        (__attribute__((address_space(3))) unsigned int*)l,
        16, 0, 0);
}

#if defined(__has_builtin) && __has_builtin(__builtin_amdgcn_mfma_f32_16x16x16bf16_1k)
__device__ __forceinline__ f32x4 mfma16(s16x4 a, s16x4 b, f32x4 c) {
    return __builtin_amdgcn_mfma_f32_16x16x16bf16_1k(a, b, c, 0, 0, 0);
}
#else
__device__ __forceinline__ f32x4 mfma16(s16x4 a, s16x4 b, f32x4 c) {
    asm volatile("v_mfma_f32_16x16x16_bf16 %0, %1, %2, %0"
                 : "+v"(c) : "v"(a), "v"(b));
    return c;
}
#endif

// ---------------------------------------------------------------------------
// bf16 GEMM:  C[M][N] = A[M][K] @ Bt[N][K]^T   (unchanged from round 2)
// ---------------------------------------------------------------------------
template <int CF32>
__global__ __launch_bounds__(256, 2)
void gemm_bt(const u16* __restrict__ A, const u16* __restrict__ B,
             void* __restrict__ Cv, int K, int lda, int ldb, int ldc)
{
    const int tid = threadIdx.x;
    const int wave = tid >> 6, lane = tid & 63;
    const int q = lane >> 4, r = lane & 15;
    const int tm = blockIdx.y, tn = blockIdx.x;

    __shared__ __align__(16) u16 Al[128 * 32];
    __shared__ __align__(16) u16 Bl[128 * 32];

    const int lr = lane & 15;
    const int lc = (lane >> 4) * 8;
    const u16* ag0 = A + (long)(tm * 128 + wave * 32 + lr) * lda + lc;
    const u16* ag1 = ag0 + 16 * (long)lda;
    const u16* bg0 = B + (long)(tn * 128 + wave * 32 + lr) * ldb + lc;
    const u16* bg1 = bg0 + 16 * (long)ldb;
    u16* al0 = &Al[wave * 1024];
    u16* al1 = &Al[wave * 1024 + 512];
    u16* bl0 = &Bl[wave * 1024];
    u16* bl1 = &Bl[wave * 1024 + 512];

    f32x4 acc[4][4] = {};
    const int cm = (wave >> 1) * 4;
    const int cn = (wave & 1) * 4;

    for (int k0 = 0; k0 < K; k0 += 32) {
        gl_lds16(ag0 + k0, al0);
        gl_lds16(ag1 + k0, al1);
        gl_lds16(bg0 + k0, bl0);
        gl_lds16(bg1 + k0, bl1);
        __syncthreads();
        bf16x8 af[4], bv[4];
        #pragma unroll
        for (int mt = 0; mt < 4; ++mt) af[mt] = *(const bf16x8*)&Al[(cm + mt) * 512 + lane * 8];
        #pragma unroll
        for (int nt = 0; nt < 4; ++nt) bv[nt] = *(const bf16x8*)&Bl[(cn + nt) * 512 + lane * 8];
        #pragma unroll
        for (int mt = 0; mt < 4; ++mt)
            #pragma unroll
            for (int nt = 0; nt < 4; ++nt)
                acc[mt][nt] = __builtin_amdgcn_mfma_f32_16x16x32_bf16(
                    af[mt], bv[nt], acc[mt][nt], 0, 0, 0);
        __syncthreads();
    }

    const int wm = (wave >> 1) * 64, wn = (wave & 1) * 64;
    const int row0 = tm * 128 + wm + q * 4;
    const int col0 = tn * 128 + wn + r;
    if (CF32) {
        float* C = (float*)Cv;
        #pragma unroll
        for (int mt = 0; mt < 4; ++mt)
            #pragma unroll
            for (int i = 0; i < 4; ++i) {
                long rb = (long)(row0 + mt * 16 + i) * ldc + col0;
                #pragma unroll
                for (int nt = 0; nt < 4; ++nt)
                    C[rb + nt * 16] = acc[mt][nt][i];
            }
    } else {
        u16* C = (u16*)Cv;
        #pragma unroll
        for (int mt = 0; mt < 4; ++mt)
            #pragma unroll
            for (int i = 0; i < 4; ++i) {
                long rb = (long)(row0 + mt * 16 + i) * ldc + col0;
                #pragma unroll
                for (int nt = 0; nt < 4; ++nt)
                    C[rb + nt * 16] = f2bf(acc[mt][nt][i]);
            }
    }
}

// ---------------------------------------------------------------------------
// Flash attention, S^T formulation.
// Block = 128 threads (2 waves), q-tile 64 (wave w: q = q0+w*32 .. +32, as
// two 16-col n-blocks). kv-tile 128. Grid (32 strips heavy-first, 16 heads).
// S^T = K·Q^T via 16x16x32 (A=K LDS chunks, B=Q regs). P^T (C-layout) feeds
// PV^T directly as B-operand of 16x16x16; A=V^T LDS chunks (2-way only).
// Maxless exp2-domain softmax (query pre-scaled by SCALE*log2e).
// ---------------------------------------------------------------------------
template<int C0, int C1>
__device__ __forceinline__ void stage_chunks(
    const u16* __restrict__ kvb, const u16* __restrict__ kpe,
    const u16* __restrict__ vt, u16* __restrict__ Kl, u16* __restrict__ Vl,
    int h, int tk, int me, int quad, int r)
{
    #pragma unroll
    for (int c = C0; c < C1; ++c) {
        if (c < 48) {
            int mtk = c / 6, kc = c % 6;
            if (mtk < me) {
                int row = tk * 128 + mtk * 16 + r;
                const u16* src = (kc < 4)
                    ? kvb + (size_t)row * 4096 + h * 256 + kc * 32 + quad * 8
                    : kpe + (size_t)row * 64 + (kc - 4) * 32 + quad * 8;
                gl_lds16(src, &Kl[c * 512]);
            }
        } else {
            int cv = c - 48, mtd = cv >> 2, sc = cv & 3;
            if (sc < (me >> 1)) {
                const u16* src = vt + ((size_t)h * 128 + mtd * 16 + r) * 2048
                                 + tk * 128 + sc * 32 + quad * 8;
                gl_lds16(src, &Vl[cv * 512]);
            }
        }
    }
}

template <int NT>
__device__ __forceinline__ void kv_tile_step(
    const u16* __restrict__ Kl, const u16* __restrict__ Vl,
    const bf16x8 (&Qf)[2][6], f32x4 (&Oacc)[8][2], float (&lsum)[2],
    int lane, int quad, int r, int kglob0, int qg0, int qg1, bool maskT)
{
    f32x4 Sacc[NT][2];
    #pragma unroll
    for (int mtk = 0; mtk < NT; ++mtk) {
        Sacc[mtk][0] = (f32x4){0.f, 0.f, 0.f, 0.f};
        Sacc[mtk][1] = (f32x4){0.f, 0.f, 0.f, 0.f};
    }
    #pragma unroll
    for (int kc = 0; kc < 6; ++kc)
        #pragma unroll
        for (int mtk = 0; mtk < NT; ++mtk) {
            bf16x8 Ak = *(const bf16x8*)&Kl[(mtk * 6 + kc) * 512 + lane * 8];
            Sacc[mtk][0] = __builtin_amdgcn_mfma_f32_16x16x32_bf16(
                Ak, Qf[0][kc], Sacc[mtk][0], 0, 0, 0);
            Sacc[mtk][1] = __builtin_amdgcn_mfma_f32_16x16x32_bf16(
                Ak, Qf[1][kc], Sacc[mtk][1], 0, 0, 0);
        }
    #pragma unroll
    for (int kb = 0; kb < NT; ++kb) {
        s16x4 Pf[2];
        const int kb0 = kglob0 + kb * 16 + quad * 4;
        #pragma unroll
        for (int n = 0; n < 2; ++n) {
            const int qg = n ? qg1 : qg0;
            #pragma unroll
            for (int i = 0; i < 4; ++i) {
                float p = exp2f(Sacc[kb][n][i]);
                if (maskT && (kb0 + i > qg)) p = 0.f;
                lsum[n] += p;
                Pf[n][i] = (short)f2bf(p);
            }
        }
        #pragma unroll
        for (int mtd = 0; mtd < 8; ++mtd) {
            s16x4 Av = *(const s16x4*)&Vl[(mtd * 4 + (kb >> 1)) * 512
                         + ((kb & 1) * 2 + (quad >> 1)) * 128 + r * 8 + (quad & 1) * 4];
            Oacc[mtd][0] = mfma16(Av, Pf[0], Oacc[mtd][0]);
            Oacc[mtd][1] = mfma16(Av, Pf[1], Oacc[mtd][1]);
        }
    }
}

__global__ __launch_bounds__(128, 1)
void flash_attn(const u16* __restrict__ query, const u16* __restrict__ kvb,
                const u16* __restrict__ kpe, const u16* __restrict__ vt,
                u16* __restrict__ ao)
{
    const int tid = threadIdx.x;
    const int w = tid >> 6, lane = tid & 63;
    const int quad = lane >> 4, r = lane & 15;
    const int j = 31 - (int)blockIdx.x;   // heavy strips first
    const int h = blockIdx.y;
    const int q0 = j * 64;
    const int ntk = (q0 >> 7) + 1;
    const int mtk_last = ((q0 & 127) + 79) >> 4;   // 4 (even j) or 8 (odd j)

    __shared__ __align__(16) u16 Kl[24576];   // 48KB: 48 chunks 16k x 32d
    __shared__ __align__(16) u16 Vl[16384];   // 32KB: 32 chunks 16d x 32s

    const int qg0 = q0 + w * 32 + r;
    const int qg1 = qg0 + 16;

    bf16x8 Qf[2][6];
    #pragma unroll
    for (int n = 0; n < 2; ++n)
        #pragma unroll
        for (int kc = 0; kc < 6; ++kc)
            Qf[n][kc] = *(const bf16x8*)(query
                + ((size_t)h * S_LEN + q0 + w * 32 + n * 16 + r) * QHEAD
                + kc * 32 + quad * 8);

    f32x4 Oacc[8][2];
    #pragma unroll
    for (int mtd = 0; mtd < 8; ++mtd) {
        Oacc[mtd][0] = (f32x4){0.f, 0.f, 0.f, 0.f};
        Oacc[mtd][1] = (f32x4){0.f, 0.f, 0.f, 0.f};
    }
    float lsum[2] = {0.f, 0.f};

    for (int tk = 0; tk < ntk; ++tk) {
        const bool last = (tk == ntk - 1);
        const int me = last ? mtk_last : 8;
        if (w == 0)
            stage_chunks<0, 40>(kvb, kpe, vt, Kl, Vl, h, tk, me, quad, r);
        else
            stage_chunks<40, 80>(kvb, kpe, vt, Kl, Vl, h, tk, me, quad, r);
        __syncthreads();
        if (me == 8)
            kv_tile_step<8>(Kl, Vl, Qf, Oacc, lsum, lane, quad, r, tk * 128, qg0, qg1, last);
        else
            kv_tile_step<4>(Kl, Vl, Qf, Oacc, lsum, lane, quad, r, tk * 128, qg0, qg1, last);
        __syncthreads();
    }

    #pragma unroll
    for (int n = 0; n < 2; ++n) {
        float l = lsum[n];
        l += __shfl_xor(l, 16, 64);
        l += __shfl_xor(l, 32, 64);
        float inv = 1.0f / l;
        const int qrow = q0 + w * 32 + n * 16 + r;
        #pragma unroll
        for (int mtd = 0; mtd < 8; ++mtd) {
            ushort4 o;
            o.x = f2bf(Oacc[mtd][n][0] * inv);
            o.y = f2bf(Oacc[mtd][n][1] * inv);
            o.z = f2bf(Oacc[mtd][n][2] * inv);
            o.w = f2bf(Oacc[mtd][n][3] * inv);
            *(ushort4*)(ao + (size_t)qrow * 2048 + h * 128 + mtd * 16 + quad * 4) = o;
        }
    }
}

// ---------------------------------------------------------------------------
__global__ __launch_bounds__(256)
void cvt_f32_bf16(const float4* __restrict__ in, ushort4* __restrict__ out, int n4)
{
    int i = blockIdx.x * 256 + threadIdx.x;
    if (i < n4) {
        float4 v = in[i];
        ushort4 o;
        o.x = f2bf(v.x); o.y = f2bf(v.y); o.z = f2bf(v.z); o.w = f2bf(v.w);
        out[i] = o;
    }
}

// in fp32 [K][N] -> out bf16 [Npad][K], rows >= N zero-filled.
__global__ __launch_bounds__(256)
void wtrans_k(const float* __restrict__ in, u16* __restrict__ out, int K, int N)
{
    __shared__ float tile[32][33];
    int k0 = blockIdx.x * 32, n0 = blockIdx.y * 32;
    int tx = threadIdx.x, ty = threadIdx.y;
    #pragma unroll
    for (int j = 0; j < 32; j += 8) {
        int n = n0 + tx;
        tile[ty + j][tx] = (n < N) ? in[(long)(k0 + ty + j) * N + n] : 0.0f;
    }
    __syncthreads();
    #pragma unroll
    for (int j = 0; j < 32; j += 8)
        out[(long)(n0 + ty + j) * K + k0 + tx] = f2bf(tile[tx][ty + j]);
}

// RMS norm in-place on first D cols of rows with stride ld.
__global__ __launch_bounds__(256)
void rmsnorm_k(u16* __restrict__ X, const float* __restrict__ w, int D, int ld)
{
    u16* row = X + (long)blockIdx.x * ld;
    const int tid = threadIdx.x;
    __shared__ float red[4];
    float sum = 0.f;
    for (int d = tid; d < D; d += 256) { float v = bf2f(row[d]); sum += v * v; }
    #pragma unroll
    for (int o = 32; o; o >>= 1) sum += __shfl_xor(sum, o, 64);
    if ((tid & 63) == 0) red[tid >> 6] = sum;
    __syncthreads();
    sum = red[0] + red[1] + red[2] + red[3];
    float scale = rsqrtf(sum / (float)D + EPS);
    for (int d = tid; d < D; d += 256)
        row[d] = f2bf(bf2f(row[d]) * scale * w[d]);
}

// qkv_a bf16 [S][2176] cols 1536.. = [c(512)|k_pe(64)] -> kv_cache fp32
// [S][576], c_norm bf16 [S][512], roped k_pe bf16 [S][64].
__global__ __launch_bounds__(256)
void kvcache_k(const u16* __restrict__ qkv, const float* __restrict__ ln,
               const int* __restrict__ pos_ids, const float* __restrict__ cosb,
               const float* __restrict__ sinb, float* __restrict__ kvout,
               u16* __restrict__ cnb, u16* __restrict__ kpe)
{
    const int s = blockIdx.x, tid = threadIdx.x;
    const u16* row = qkv + (long)s * 2176 + 1536;
    __shared__ float red[4];
    float sum = 0.f;
    for (int d = tid; d < 512; d += 256) { float v = bf2f(row[d]); sum += v * v; }
    #pragma unroll
    for (int o = 32; o; o >>= 1) sum += __shfl_xor(sum, o, 64);
    if ((tid & 63) == 0) red[tid >> 6] = sum;
    __syncthreads();
    sum = red[0] + red[1] + red[2] + red[3];
    float scale = rsqrtf(sum / 512.f + EPS);
    for (int d = tid; d < 512; d += 256) {
        float v = bf2f(row[d]) * scale * ln[d];
        kvout[(long)s * 576 + d] = v;
        cnb[(long)s * 512 + d] = f2bf(v);
    }
    if (tid < 32) {
        int p = pos_ids[s];
        float x0 = bf2f(row[512 + 2 * tid]);
        float x1 = bf2f(row[512 + 2 * tid + 1]);
        float c1 = cosb[p * 64 + tid], s1 = sinb[p * 64 + tid];
        float c2 = cosb[p * 64 + 32 + tid], s2 = sinb[p * 64 + 32 + tid];
        float lo = x0 * c1 - x1 * s1;
        float hi = x1 * c2 + x0 * s2;
        kvout[(long)s * 576 + 512 + tid] = lo;
        kvout[(long)s * 576 + 544 + tid] = hi;
        kpe[(long)s * 64 + tid] = f2bf(lo);
        kpe[(long)s * 64 + 32 + tid] = f2bf(hi);
    }
}

// q bf16 [S][3072] -> query bf16 [H][S][192], rope on last 64 dims,
// all values pre-scaled by SCALE*log2(e) for exp2-domain softmax.
__global__ __launch_bounds__(256)
void qrope_k(const u16* __restrict__ qb, const int* __restrict__ pos_ids,
             const float* __restrict__ cosb, const float* __restrict__ sinb,
             u16* __restrict__ query)
{
    const int s = blockIdx.x, tid = threadIdx.x;
    const u16* row = qb + (long)s * 3072;
    {   // nope part: 16 heads x 16 chunks of 8, scaled
        int h = tid >> 4, c = tid & 15;
        const u16* src = &row[h * QHEAD + c * 8];
        u16* dst = &query[((long)(h * S_LEN + s)) * QHEAD + c * 8];
        ushort4 a = *(const ushort4*)src;
        ushort4 b = *(const ushort4*)(src + 4);
        ushort4 oa, ob;
        oa.x = f2bf(bf2f(a.x) * QSCALE_LOG2E); oa.y = f2bf(bf2f(a.y) * QSCALE_LOG2E);
        oa.z = f2bf(bf2f(a.z) * QSCALE_LOG2E); oa.w = f2bf(bf2f(a.w) * QSCALE_LOG2E);
        ob.x = f2bf(bf2f(b.x) * QSCALE_LOG2E); ob.y = f2bf(bf2f(b.y) * QSCALE_LOG2E);
        ob.z = f2bf(bf2f(b.z) * QSCALE_LOG2E); ob.w = f2bf(bf2f(b.w) * QSCALE_LOG2E);
        *(ushort4*)dst = oa;
        *(ushort4*)(dst + 4) = ob;
    }
    int p = pos_ids[s];
    for (int idx = tid; idx < 512; idx += 256) {
        int h = idx >> 5, i = idx & 31;
        float x0 = bf2f(row[h * QHEAD + 128 + 2 * i]);
        float x1 = bf2f(row[h * QHEAD + 128 + 2 * i + 1]);
        float c1 = cosb[p * 64 + i], s1 = sinb[p * 64 + i];
        float c2 = cosb[p * 64 + 32 + i], s2 = sinb[p * 64 + 32 + i];
        u16* qr = query + ((long)(h * S_LEN + s)) * QHEAD;
        qr[128 + i] = f2bf((x0 * c1 - x1 * s1) * QSCALE_LOG2E);
        qr[160 + i] = f2bf((x1 * c2 + x0 * s2) * QSCALE_LOG2E);
    }
}

// kv bf16 [S][4096] value part -> vt bf16 [H*128][S] (transposed)
__global__ __launch_bounds__(256)
void vtrans_k(const u16* __restrict__ kv, u16* __restrict__ vt)
{
    __shared__ u16 tile[32][33];
    int s0 = blockIdx.x * 32, d0 = blockIdx.y * 32, h = blockIdx.z;
    int tx = threadIdx.x, ty = threadIdx.y;
    #pragma unroll
    for (int j = 0; j < 32; j += 8)
        tile[ty + j][tx] = kv[(long)(s0 + ty + j) * 4096 + h * 256 + 128 + d0 + tx];
    __syncthreads();
    #pragma unroll
    for (int j = 0; j < 32; j += 8)
        vt[(long)(h * 128 + d0 + ty + j) * S_LEN + s0 + tx] = tile[tx][ty + j];
}

// ---------------------------------------------------------------------------
extern "C" void kernel_launch(void* const* d_in, const int* in_sizes, int n_in,
                              void* d_out, int out_size, void* d_ws, size_t ws_size,
                              hipStream_t stream)
{
    const float* x      = (const float*)d_in[0];
    const int*   posid  = (const int*)d_in[2];
    const float* cosb   = (const float*)d_in[3];
    const float* sinb   = (const float*)d_in[4];
    const float* q_a_w  = (const float*)d_in[5];
    const float* q_a_ln = (const float*)d_in[6];
    const float* q_b_w  = (const float*)d_in[7];
    const float* kv_a_w = (const float*)d_in[8];
    const float* kv_a_ln= (const float*)d_in[9];
    const float* kv_b_w = (const float*)d_in[10];
    const float* o_w    = (const float*)d_in[11];

    float* out    = (float*)d_out;
    float* kv_out = out + (size_t)2048 * 2048;

    char* ws = (char*)d_ws;
    size_t off = 0;
    auto alloc = [&](size_t bytes) { char* p = ws + off; off += (bytes + 255) & ~(size_t)255; return p; };
    u16* xb    = (u16*)alloc(2048ULL * 2048 * 2);
    u16* W1    = (u16*)alloc(2176ULL * 2048 * 2);   // [q_a^T ; kv_a^T(pad 640)]
    u16* qbwt  = (u16*)alloc(3072ULL * 1536 * 2);
    u16* kvbwt = (u16*)alloc(4096ULL * 512 * 2);
    u16* owt   = (u16*)alloc(2048ULL * 2048 * 2);
    u16* qkv_a = (u16*)alloc(2048ULL * 2176 * 2);   // [q_a(1536) | ckv(640)]
    u16* qbuf  = (u16*)alloc(2048ULL * 3072 * 2);
    u16* query = (u16*)alloc(16ULL * 2048 * 192 * 2);
    u16* cnb   = (u16*)alloc(2048ULL * 512 * 2);
    u16* kpe   = (u16*)alloc(2048ULL * 64 * 2);
    u16* kvbuf = (u16*)alloc(2048ULL * 4096 * 2);
    u16* vt    = (u16*)alloc(16ULL * 128 * 2048 * 2);
    u16* ao    = (u16*)alloc(2048ULL * 2048 * 2);
    (void)ws_size; (void)in_sizes; (void)n_in; (void)out_size;

    dim3 blk(256);
    dim3 tblk(32, 8);

    // 0) conversions / weight transposes
    cvt_f32_bf16<<<dim3(4096), blk, 0, stream>>>((const float4*)x, (ushort4*)xb, 2048 * 2048 / 4);
    wtrans_k<<<dim3(64, 48),  tblk, 0, stream>>>(q_a_w,  W1,                    2048, 1536);
    wtrans_k<<<dim3(64, 20),  tblk, 0, stream>>>(kv_a_w, W1 + 1536ULL * 2048,   2048, 576);
    wtrans_k<<<dim3(48, 96),  tblk, 0, stream>>>(q_b_w,  qbwt,  1536, 3072);
    wtrans_k<<<dim3(16, 128), tblk, 0, stream>>>(kv_b_w, kvbwt, 512,  4096);
    wtrans_k<<<dim3(64, 64),  tblk, 0, stream>>>(o_w,    owt,   2048, 2048);

    // 1) [q_a | ckv] = x @ [q_a_w | kv_a_w]  (merged, N=2176)
    gemm_bt<0><<<dim3(17, 16), blk, 0, stream>>>(xb, W1, qkv_a, 2048, 2048, 2048, 2176);
    rmsnorm_k<<<dim3(2048), blk, 0, stream>>>(qkv_a, q_a_ln, 1536, 2176);
    kvcache_k<<<dim3(2048), blk, 0, stream>>>(qkv_a, kv_a_ln, posid, cosb, sinb, kv_out, cnb, kpe);

    // 2) q = q_a_norm @ q_b_w ; rope + relayout (+ exp2-domain pre-scale)
    gemm_bt<0><<<dim3(24, 16), blk, 0, stream>>>(qkv_a, qbwt, qbuf, 1536, 2176, 1536, 3072);
    qrope_k<<<dim3(2048), blk, 0, stream>>>(qbuf, posid, cosb, sinb, query);

    // 3) kv = c_norm @ kv_b_w ; transpose value
    gemm_bt<0><<<dim3(32, 16), blk, 0, stream>>>(cnb, kvbwt, kvbuf, 512, 512, 512, 4096);
    vtrans_k<<<dim3(64, 4, 16), tblk, 0, stream>>>(kvbuf, vt);

    // 4) fused flash attention (S^T form) -> ao bf16 [S][H*128]
    flash_attn<<<dim3(32, 16), dim3(128), 0, stream>>>(query, kvbuf, kpe, vt, ao);

    // 5) out = ao @ o_w (fp32)
    gemm_bt<1><<<dim3(16, 16), blk, 0, stream>>>(ao, owt, out, 2048, 2048, 2048, 2048);
}